// Round 14
// baseline (199.959 us; speedup 1.0000x reference)
//
#include <hip/hip_runtime.h>
#include <hip/hip_bf16.h>

// DomainEncoder: 8-expert MoE MLP, N=32768, 256 -> 1024 (LN+ReLU) -> 256.
// Round-14 vs round-13 (199.6 us, best): dispatch-count reduction only;
// GEMM inner loops byte-identical (12 rounds of ablation say they're at the
// 2-phase structural plateau).
//   - make_meta + META ELIMINATED: each GEMM block derives (dom, m0) from
//     counts[8] via a ~30-SALU prefix scan (uniform, scalar-cached).
//   - CURSORS zero-init folded into the 64B memset; assign_pos computes the
//     domain base offsets itself from counts.
//   - POS eliminated: copy_rows is perm-driven (grid over destination p,
//     perm[p] < 0 -> skip; per-wave row reads stay contiguous/coalesced).

#define ND 8
#define NROWS 32768
#define DIN 256
#define DHID 1024
#define DOUT 256
#define MPAD 33792          // 32768 + 8*128 worst-case padding
#define NTILES 264          // 256 + 8 worst-case row tiles (264 = 8*33)

typedef short short8 __attribute__((ext_vector_type(8)));
typedef float floatx4 __attribute__((ext_vector_type(4)));

__device__ __forceinline__ unsigned short f2bf(float f) {
    unsigned u = __builtin_bit_cast(unsigned, f);
    unsigned r = u + 0x7fff + ((u >> 16) & 1);   // RNE (inputs finite)
    return (unsigned short)(r >> 16);
}
__device__ __forceinline__ float bf2f(unsigned short h) {
    unsigned u = ((unsigned)h) << 16;
    return __builtin_bit_cast(float, u);
}

// (dom, m0) for a 128-row tile index, from domain counts (128-aligned bins).
__device__ __forceinline__ int2 tile_meta(const int* __restrict__ counts, int tile) {
    int off = 0;
#pragma unroll
    for (int d = 0; d < ND; d++) {
        const int nt = (counts[d] + 127) >> 7;
        if (tile < nt) return make_int2(d, off + (tile << 7));
        tile -= nt;
        off += nt << 7;
    }
    return make_int2(-1, 0);
}

#define GLDS16(gp, lp) __builtin_amdgcn_global_load_lds( \
    (const __attribute__((address_space(1))) void*)(gp), \
    (__attribute__((address_space(3))) void*)(lp), 16, 0, 0)

// ---------------- 1. prep1: transposes | perm-init | histogram ---------------
// blocks [0,2048): W1 transpose; [2048,4096): W2 transpose;
// [4096,4228): perm init (132x256 >= MPAD); [4228,4356): histogram (128x256).
// COUNTS+CURSORS zeroed by hipMemsetAsync (64B) before this dispatch.
__global__ void prep1(const float* __restrict__ W1, unsigned short* __restrict__ W1T,
                      const float* __restrict__ W2, unsigned short* __restrict__ W2T,
                      const int* __restrict__ dt, int* __restrict__ perm,
                      int* __restrict__ counts) {
    const int tid = threadIdx.x;
    int b = blockIdx.x;
    if (b >= 4096) {
        const int bi = b - 4096;
        if (bi < 132) {                      // perm init
            const int i = bi * 256 + tid;
            if (i < MPAD) perm[i] = -1;
        } else {                             // histogram (block-aggregated)
            __shared__ int lc[ND];
            if (tid < ND) lc[tid] = 0;
            __syncthreads();
            atomicAdd(&lc[dt[(bi - 132) * 256 + tid]], 1);
            __syncthreads();
            if (tid < ND && lc[tid] > 0) atomicAdd(&counts[tid], lc[tid]);
        }
        return;
    }
    __shared__ float t[32][33];
    const float* in; unsigned short* out; int R, C, bx, by, z;
    if (b < 2048) {           // W1: R=DIN, C=DHID
        in = W1; out = W1T; R = DIN; C = DHID;
        bx = b & 31; by = (b >> 5) & 7; z = b >> 8;
    } else {                  // W2: R=DHID, C=DOUT
        b -= 2048;
        in = W2; out = W2T; R = DHID; C = DOUT;
        bx = b & 7; by = (b >> 3) & 31; z = b >> 8;
    }
    const int c0 = bx * 32, r0 = by * 32;
    const int tx = tid & 31, ty = tid >> 5;   // 32x8
    const float* src = in + (size_t)z * R * C;
    unsigned short* dst = out + (size_t)z * R * C;
#pragma unroll
    for (int i = 0; i < 32; i += 8)
        t[ty + i][tx] = src[(size_t)(r0 + ty + i) * C + c0 + tx];
    __syncthreads();
#pragma unroll
    for (int i = 0; i < 32; i += 8)
        dst[(size_t)(c0 + ty + i) * R + r0 + tx] = f2bf(t[tx][ty + i]);
}

// ---------------- 2. position assignment (self-computed bases) ----------------
// 8 global atomics per 256 rows; cursors pre-zeroed; base[d] from counts scan.
__global__ __launch_bounds__(256)
void assign_pos(const int* __restrict__ dt, const int* __restrict__ counts,
                int* __restrict__ cursors, int* __restrict__ perm) {
    __shared__ int lcnt[ND];
    __shared__ int lbase[ND];
    const int tid = threadIdx.x;
    if (tid < ND) lcnt[tid] = 0;
    __syncthreads();
    const int r = blockIdx.x * 256 + tid;
    const int d = dt[r];
    const int myrank = atomicAdd(&lcnt[d], 1);   // LDS atomic: cheap
    __syncthreads();
    if (tid < ND) {
        int base = 0;
        for (int dd = 0; dd < tid; dd++) base += ((counts[dd] + 127) >> 7) << 7;
        lbase[tid] = base + (lcnt[tid] > 0 ? atomicAdd(&cursors[tid], lcnt[tid]) : 0);
    }
    __syncthreads();
    perm[lbase[d] + myrank] = r;
}

// ---------------- 3. gather copy (perm-driven): one wave per dest row ---------
__global__ __launch_bounds__(256)
void copy_rows(const float* __restrict__ x, const int* __restrict__ perm,
               unsigned short* __restrict__ xs) {
    const int tid = threadIdx.x;
    const int lane = tid & 63;
    const int p = blockIdx.x * 4 + (tid >> 6);           // 4 dest rows per block
    const int r = perm[p];
    if (r < 0) return;                                   // padding row
    float4 v = ((const float4*)(x + (size_t)r * DIN))[lane];   // 16B/lane read
    ushort4 o;
    o.x = f2bf(v.x); o.y = f2bf(v.y); o.z = f2bf(v.z); o.w = f2bf(v.w);
    ((ushort4*)(xs + (size_t)p * DIN))[lane] = o;              // 8B/lane write
}

// ---------------- 4. GEMM-A: H = XS @ W1^T + b1, LN partials ------------------
// 128x128 tile, 4 waves 2x2, BK=32, dbuf single-barrier (round-5 structure).
__global__ __launch_bounds__(256, 2)
void gemm_a(const unsigned short* __restrict__ A,
            const unsigned short* __restrict__ Bt,
            const float* __restrict__ bias,
            const int* __restrict__ counts,
            unsigned short* __restrict__ Cbf,
            float2* __restrict__ spart) {
    constexpr int K = DIN, Ntot = DHID, NB = 8, NWG = NTILES * NB, NS = K / 32;
    const int bid = (int)blockIdx.x;
    const int wid = (bid & 7) * (NWG >> 3) + (bid >> 3);
    const int tile = wid / NB;
    const int n0 = (wid % NB) * 128;
    const int2 md = tile_meta(counts, tile);
    const int dom = md.x;
    if (dom < 0) return;
    const int m0 = md.y;

    __shared__ unsigned short As[2][128 * 32];
    __shared__ unsigned short Bs[2][128 * 32];
    __shared__ float sred[2][128];

    const int tid = threadIdx.x;
    const int lane = tid & 63;
    const int w = tid >> 6;
    const int wr = w >> 1, wc = w & 1;
    const int l15 = lane & 15;

    const unsigned short* Abase = A + (size_t)m0 * K;
    const unsigned short* Bbase = Bt + (size_t)dom * Ntot * K + (size_t)n0 * K;

    if (tid < 128) { sred[0][tid] = 0.f; sred[1][tid] = 0.f; }

#define STAGE_AB(buf, t_) {                                                    \
        const int k0_ = (t_) * 32;                                             \
        _Pragma("unroll")                                                      \
        for (int it = 0; it < 2; ++it) {                                       \
            const int c = w * 128 + it * 64 + lane;                            \
            const int m_ = c >> 2, kcc = c & 3;                                \
            GLDS16(Bbase + (size_t)m_ * K + k0_ + kcc * 8,                     \
                   &Bs[buf][(w * 128 + it * 64) * 8]);                         \
            GLDS16(Abase + (size_t)m_ * K + k0_ + kcc * 8,                     \
                   &As[buf][(w * 128 + it * 64) * 8]);                         \
        }                                                                      \
    }

    floatx4 acc[4][4];
#pragma unroll
    for (int i = 0; i < 4; i++)
#pragma unroll
        for (int j = 0; j < 4; j++) acc[i][j] = 0.f;

    STAGE_AB(0, 0)
    __syncthreads();

    int cur = 0;
    const int kk = (lane >> 4) * 8;
    for (int t = 0; t < NS - 1; ++t) {
        const int nx = cur ^ 1;
        STAGE_AB(nx, t + 1)
        short8 a[4], b[4];
#pragma unroll
        for (int i = 0; i < 4; i++) {
            const int m = wr * 64 + i * 16 + l15;
            a[i] = *(const short8*)&As[cur][m * 32 + kk];
            const int n = wc * 64 + i * 16 + l15;
            b[i] = *(const short8*)&Bs[cur][n * 32 + kk];
        }
        __builtin_amdgcn_s_setprio(1);
#pragma unroll
        for (int i = 0; i < 4; i++)
#pragma unroll
            for (int j = 0; j < 4; j++)
                acc[i][j] = __builtin_amdgcn_mfma_f32_16x16x32_bf16(a[i], b[j], acc[i][j], 0, 0, 0);
        __builtin_amdgcn_s_setprio(0);
        __syncthreads();
        cur = nx;
    }
    {
        short8 a[4], b[4];
#pragma unroll
        for (int i = 0; i < 4; i++) {
            const int m = wr * 64 + i * 16 + l15;
            a[i] = *(const short8*)&As[cur][m * 32 + kk];
            const int n = wc * 64 + i * 16 + l15;
            b[i] = *(const short8*)&Bs[cur][n * 32 + kk];
        }
        __builtin_amdgcn_s_setprio(1);
#pragma unroll
        for (int i = 0; i < 4; i++)
#pragma unroll
            for (int j = 0; j < 4; j++)
                acc[i][j] = __builtin_amdgcn_mfma_f32_16x16x32_bf16(a[i], b[j], acc[i][j], 0, 0, 0);
        __builtin_amdgcn_s_setprio(0);
    }
#undef STAGE_AB

    // epilogue: write H = h+b1 (bf16) + per-row LN partials
    const int quad = lane >> 4;
    float bv[4];
#pragma unroll
    for (int j = 0; j < 4; j++)
        bv[j] = bias[dom * Ntot + n0 + wc * 64 + j * 16 + l15];
#pragma unroll
    for (int i = 0; i < 4; i++) {
#pragma unroll
        for (int r = 0; r < 4; r++) {
            const int rl = wr * 64 + i * 16 + quad * 4 + r;
            float s = 0.f, s2 = 0.f;
#pragma unroll
            for (int j = 0; j < 4; j++) {
                const float v = acc[i][j][r] + bv[j];
                Cbf[(size_t)(m0 + rl) * Ntot + n0 + wc * 64 + j * 16 + l15] = f2bf(v);
                s += v; s2 += v * v;
            }
#pragma unroll
            for (int o = 8; o; o >>= 1) {
                s  += __shfl_xor(s, o, 64);
                s2 += __shfl_xor(s2, o, 64);
            }
            if (l15 == 0) {
                atomicAdd(&sred[0][rl], s);
                atomicAdd(&sred[1][rl], s2);
            }
        }
    }
    __syncthreads();
    if (tid < 128)
        spart[(size_t)(n0 >> 7) * MPAD + m0 + tid] =
            make_float2(sred[0][tid], sred[1][tid]);
}

// ---------------- 5. GEMM-B: out = LN_ReLU(H) @ W2^T + b2 --------------------
// Round-5 exact: 128x128 tile, BK=32, dbuf single-barrier, A reg-staged with
// LN+ReLU transform (spart stats, gamma/beta from LDS), scatter via perm.
__global__ __launch_bounds__(256, 2)
void gemm_b(const unsigned short* __restrict__ H,
            const unsigned short* __restrict__ W2T,
            const float* __restrict__ b2,
            const int* __restrict__ counts,
            const int* __restrict__ perm,
            float* __restrict__ out,
            const float2* __restrict__ spart,
            const float* __restrict__ gamma,
            const float* __restrict__ beta) {
    constexpr int K = DHID;
    constexpr int NWG = NTILES * 2;           // 528
    constexpr int NS = K / 32;                // 32 steps
    const int bid = (int)blockIdx.x;
    const int wid = (bid & 7) * (NWG >> 3) + (bid >> 3);
    const int tile = wid >> 1;
    const int n0 = (wid & 1) * 128;
    const int2 md = tile_meta(counts, tile);
    const int dom = md.x;
    if (dom < 0) return;
    const int m0 = md.y;

    __shared__ unsigned short As[2][128 * 32];   // 2 x 8 KB
    __shared__ unsigned short Bs[2][128 * 32];   // 2 x 8 KB
    __shared__ float gb[2048];                   // gamma[1024] beta[1024]

    const int tid = threadIdx.x;
    const int lane = tid & 63;
    const int w = tid >> 6;
    const int wr = w >> 1, wc = w & 1;
    const int l15 = lane & 15;

    const unsigned short* Hbase = H + (size_t)m0 * K;
    const unsigned short* Bbase = W2T + (size_t)dom * DOUT * K + (size_t)n0 * K;

    // gamma/beta -> LDS (read after the first barrier)
    ((float4*)gb)[tid] = ((const float4*)(gamma + dom * DHID))[tid];
    ((float4*)(gb + 1024))[tid] = ((const float4*)(beta + dom * DHID))[tid];

    const int ma = (w * 128 + lane) >> 2;    // staged rows ma, ma+16
    const int kc = lane & 3;                 // fixed 16B k-chunk within 32
    float muv[2], rsv[2];
#pragma unroll
    for (int h2 = 0; h2 < 2; ++h2) {
        const int rm = m0 + ma + h2 * 16;
        float s = 0.f, s2 = 0.f;
#pragma unroll
        for (int nb = 0; nb < 8; ++nb) {
            const float2 p = spart[(size_t)nb * MPAD + rm];
            s += p.x; s2 += p.y;
        }
        const float mu = s * (1.f / 1024.f);
        const float var = fmaxf(s2 * (1.f / 1024.f) - mu * mu, 0.f);
        muv[h2] = mu;
        rsv[h2] = rsqrtf(var + 1e-5f);
    }
    short8 hv0{}, hv1{};

#define LOAD_H(t_) {                                                           \
        const int k0_ = (t_) * 32 + kc * 8;                                    \
        hv0 = *(const short8*)(Hbase + (size_t)ma * K + k0_);                  \
        hv1 = *(const short8*)(Hbase + (size_t)(ma + 16) * K + k0_);           \
    }
#define XFRM(buf, t_) {                                                        \
        const int k1 = (t_) * 32 + kc * 8;                                     \
        const float4 g0 = *(const float4*)&gb[k1];                             \
        const float4 g1 = *(const float4*)&gb[k1 + 4];                         \
        const float4 e0 = *(const float4*)&gb[1024 + k1];                      \
        const float4 e1 = *(const float4*)&gb[1024 + k1 + 4];                  \
        const float gA[8] = {g0.x, g0.y, g0.z, g0.w, g1.x, g1.y, g1.z, g1.w};  \
        const float eA[8] = {e0.x, e0.y, e0.z, e0.w, e1.x, e1.y, e1.z, e1.w};  \
        _Pragma("unroll")                                                      \
        for (int h2 = 0; h2 < 2; ++h2) {                                       \
            const float mu = muv[h2], rs = rsv[h2];                            \
            const short8 hvv = h2 ? hv1 : hv0;                                 \
            short8 o;                                                          \
            _Pragma("unroll")                                                  \
            for (int e = 0; e < 8; ++e) {                                      \
                const float rg = gA[e] * rs;                                   \
                const float v = fmaxf(fmaf(bf2f((unsigned short)hvv[e]), rg,   \
                                           fmaf(-mu, rg, eA[e])), 0.f);        \
                o[e] = (short)f2bf(v);                                         \
            }                                                                  \
            *(short8*)&As[buf][(w * 128 + h2 * 64 + lane) * 8] = o;            \
        }                                                                      \
    }
#define STAGE_B(buf, t_) {                                                     \
        const int k0_ = (t_) * 32;                                             \
        _Pragma("unroll")                                                      \
        for (int it = 0; it < 2; ++it) {                                       \
            const int c = w * 128 + it * 64 + lane;                            \
            const int m_ = c >> 2, kcc = c & 3;                                \
            GLDS16(Bbase + (size_t)m_ * K + k0_ + kcc * 8,                     \
                   &Bs[buf][(w * 128 + it * 64) * 8]);                         \
        }                                                                      \
    }

    floatx4 acc[4][4];
#pragma unroll
    for (int i = 0; i < 4; i++)
#pragma unroll
        for (int j = 0; j < 4; j++) acc[i][j] = 0.f;

    // prologue
    STAGE_B(0, 0)
    LOAD_H(0)
    __syncthreads();       // gb LDS writes visible to all waves
    XFRM(0, 0)             // uses H(0) regs (auto-waited)
    LOAD_H(1)
    __syncthreads();       // As[0] ds_writes + Bs[0] GLDS drained

    int cur = 0;
    const int kk = (lane >> 4) * 8;
    for (int t = 0; t < NS - 1; ++t) {
        const int nx = cur ^ 1;
        STAGE_B(nx, t + 1)
        XFRM(nx, t + 1)                 // uses H(t+1)
        if (t + 2 < NS) LOAD_H(t + 2)
        short8 a[4], b[4];
#pragma unroll
        for (int i = 0; i < 4; i++) {
            const int m = wr * 64 + i * 16 + l15;
            a[i] = *(const short8*)&As[cur][m * 32 + kk];
            const int n = wc * 64 + i * 16 + l15;
            b[i] = *(const short8*)&Bs[cur][n * 32 + kk];
        }
        __builtin_amdgcn_s_setprio(1);
#pragma unroll
        for (int i = 0; i < 4; i++)
#pragma unroll
            for (int j = 0; j < 4; j++)
                acc[i][j] = __builtin_amdgcn_mfma_f32_16x16x32_bf16(a[i], b[j], acc[i][j], 0, 0, 0);
        __builtin_amdgcn_s_setprio(0);
        __syncthreads();
        cur = nx;
    }
    {
        short8 a[4], b[4];
#pragma unroll
        for (int i = 0; i < 4; i++) {
            const int m = wr * 64 + i * 16 + l15;
            a[i] = *(const short8*)&As[cur][m * 32 + kk];
            const int n = wc * 64 + i * 16 + l15;
            b[i] = *(const short8*)&Bs[cur][n * 32 + kk];
        }
        __builtin_amdgcn_s_setprio(1);
#pragma unroll
        for (int i = 0; i < 4; i++)
#pragma unroll
            for (int j = 0; j < 4; j++)
                acc[i][j] = __builtin_amdgcn_mfma_f32_16x16x32_bf16(a[i], b[j], acc[i][j], 0, 0, 0);
        __builtin_amdgcn_s_setprio(0);
    }
#undef LOAD_H
#undef XFRM
#undef STAGE_B

    // epilogue: scatter out = acc + b2 via perm (padding rows skipped)
    const int quad = lane >> 4;
    float bv[4];
#pragma unroll
    for (int j = 0; j < 4; j++)
        bv[j] = b2[dom * DOUT + n0 + wc * 64 + j * 16 + l15];
#pragma unroll
    for (int i = 0; i < 4; i++) {
        const int rowbase = m0 + wr * 64 + i * 16 + quad * 4;
#pragma unroll
        for (int r = 0; r < 4; r++) {
            const int orig = perm[rowbase + r];
            if (orig < 0) continue;     // padding row
#pragma unroll
            for (int j = 0; j < 4; j++) {
                const int col = n0 + wc * 64 + j * 16 + l15;
                out[(size_t)orig * DOUT + col] = acc[i][j][r] + bv[j];
            }
        }
    }
}

// ---------------- launch ------------------------------------------------------
extern "C" void kernel_launch(void* const* d_in, const int* in_sizes, int n_in,
                              void* d_out, int out_size, void* d_ws, size_t ws_size,
                              hipStream_t stream) {
    const float* x = (const float*)d_in[0];
    const int* dt = (const int*)d_in[1];
    const float* W1 = (const float*)d_in[2];
    const float* b1 = (const float*)d_in[3];
    const float* gamma = (const float*)d_in[4];
    const float* beta = (const float*)d_in[5];
    const float* W2 = (const float*)d_in[6];
    const float* b2 = (const float*)d_in[7];
    float* out = (float*)d_out;

    char* ws = (char*)d_ws;
    size_t off = 0;
    auto take = [&](size_t nbytes) -> char* {
        char* p = ws + off;
        off = (off + nbytes + 255) & ~(size_t)255;
        return p;
    };
    unsigned short* W1T = (unsigned short*)take((size_t)ND * DHID * DIN * 2);
    unsigned short* W2T = (unsigned short*)take((size_t)ND * DOUT * DHID * 2);
    unsigned short* XS  = (unsigned short*)take((size_t)MPAD * DIN * 2);
    unsigned short* H   = (unsigned short*)take((size_t)MPAD * DHID * 2);
    float2* SPART = (float2*)take((size_t)8 * MPAD * 8);
    int* PERM   = (int*)take(MPAD * 4);
    int* CNT    = (int*)take(64);            // counts[8] then cursors[8]
    (void)ws_size; (void)n_in; (void)in_sizes; (void)out_size;

    int* COUNTS = CNT;
    int* CURSORS = CNT + 8;

    hipMemsetAsync(CNT, 0, 64, stream);      // counts + cursors
    prep1<<<4356, 256, 0, stream>>>(W1, W1T, W2, W2T, dt, PERM, COUNTS);
    assign_pos<<<NROWS / 256, 256, 0, stream>>>(dt, COUNTS, CURSORS, PERM);
    copy_rows<<<MPAD / 4, 256, 0, stream>>>(x, PERM, XS);
    gemm_a<<<NTILES * 8, 256, 0, stream>>>(XS, W1T, b1, COUNTS, H, SPART);
    gemm_b<<<NTILES * 2, 256, 0, stream>>>(H, W2T, b2, COUNTS, PERM, out,
                                           SPART, gamma, beta);
}

// Round 15
// 198.638 us; speedup vs baseline: 1.0067x; 1.0067x over previous
//
#include <hip/hip_runtime.h>
#include <hip/hip_bf16.h>

// DomainEncoder: 8-expert MoE MLP, N=32768, 256 -> 1024 (LN+ReLU) -> 256.
// Round-15 vs round-14 (199.96; tile_meta's 8 serial scalar loads cost each
// GEMM ~6 us, offsetting the make_meta dispatch savings):
//   - META table RESTORED for both GEMMs (round-13 form, one int2 load/block;
//     GEMM inner loops byte-identical to the proven 50-51 us versions).
//   - META computed INSIDE the assign dispatch: grid 129; blocks 0-127 do
//     position assignment (round-14 self-computed-base form, cursors zeroed
//     by the 64B memset), block 128 builds META. Disjoint, concurrent.
//   - copy_rows perm-driven (round-14, proven; POS stays eliminated).
//   - dispatches: memset + prep1 + assign_meta + copy_rows + gemm_a + gemm_b.

#define ND 8
#define NROWS 32768
#define DIN 256
#define DHID 1024
#define DOUT 256
#define MPAD 33792          // 32768 + 8*128 worst-case padding
#define NTILES 264          // 256 + 8 worst-case row tiles (264 = 8*33)

typedef short short8 __attribute__((ext_vector_type(8)));
typedef float floatx4 __attribute__((ext_vector_type(4)));

__device__ __forceinline__ unsigned short f2bf(float f) {
    unsigned u = __builtin_bit_cast(unsigned, f);
    unsigned r = u + 0x7fff + ((u >> 16) & 1);   // RNE (inputs finite)
    return (unsigned short)(r >> 16);
}
__device__ __forceinline__ float bf2f(unsigned short h) {
    unsigned u = ((unsigned)h) << 16;
    return __builtin_bit_cast(float, u);
}

#define GLDS16(gp, lp) __builtin_amdgcn_global_load_lds( \
    (const __attribute__((address_space(1))) void*)(gp), \
    (__attribute__((address_space(3))) void*)(lp), 16, 0, 0)

// ---------------- 1. prep1: transposes | perm-init | histogram ---------------
// blocks [0,2048): W1 transpose; [2048,4096): W2 transpose;
// [4096,4228): perm init (132x256 >= MPAD); [4228,4356): histogram (128x256).
// COUNTS+CURSORS zeroed by hipMemsetAsync (64B) before this dispatch.
__global__ void prep1(const float* __restrict__ W1, unsigned short* __restrict__ W1T,
                      const float* __restrict__ W2, unsigned short* __restrict__ W2T,
                      const int* __restrict__ dt, int* __restrict__ perm,
                      int* __restrict__ counts) {
    const int tid = threadIdx.x;
    int b = blockIdx.x;
    if (b >= 4096) {
        const int bi = b - 4096;
        if (bi < 132) {                      // perm init
            const int i = bi * 256 + tid;
            if (i < MPAD) perm[i] = -1;
        } else {                             // histogram (block-aggregated)
            __shared__ int lc[ND];
            if (tid < ND) lc[tid] = 0;
            __syncthreads();
            atomicAdd(&lc[dt[(bi - 132) * 256 + tid]], 1);
            __syncthreads();
            if (tid < ND && lc[tid] > 0) atomicAdd(&counts[tid], lc[tid]);
        }
        return;
    }
    __shared__ float t[32][33];
    const float* in; unsigned short* out; int R, C, bx, by, z;
    if (b < 2048) {           // W1: R=DIN, C=DHID
        in = W1; out = W1T; R = DIN; C = DHID;
        bx = b & 31; by = (b >> 5) & 7; z = b >> 8;
    } else {                  // W2: R=DHID, C=DOUT
        b -= 2048;
        in = W2; out = W2T; R = DHID; C = DOUT;
        bx = b & 7; by = (b >> 3) & 31; z = b >> 8;
    }
    const int c0 = bx * 32, r0 = by * 32;
    const int tx = tid & 31, ty = tid >> 5;   // 32x8
    const float* src = in + (size_t)z * R * C;
    unsigned short* dst = out + (size_t)z * R * C;
#pragma unroll
    for (int i = 0; i < 32; i += 8)
        t[ty + i][tx] = src[(size_t)(r0 + ty + i) * C + c0 + tx];
    __syncthreads();
#pragma unroll
    for (int i = 0; i < 32; i += 8)
        dst[(size_t)(c0 + ty + i) * R + r0 + tx] = f2bf(t[tx][ty + i]);
}

// ---------------- 2. assign_meta: position assignment | META build -----------
// blocks 0..127: counting-sort position assignment (cursors pre-zeroed;
// per-domain base computed from counts). block 128: META table.
__global__ __launch_bounds__(256)
void assign_meta(const int* __restrict__ dt, const int* __restrict__ counts,
                 int* __restrict__ cursors, int* __restrict__ perm,
                 int2* __restrict__ meta) {
    const int tid = threadIdx.x;
    if (blockIdx.x == 128) {                 // ---- META build ----
        __shared__ int base[ND], ntc[ND];
        if (tid == 0) {
            int off = 0;
            for (int d = 0; d < ND; d++) {
                base[d] = off;
                ntc[d] = (counts[d] + 127) >> 7;
                off += ntc[d] << 7;
            }
        }
        __syncthreads();
        for (int i = tid; i < NTILES; i += 256) {
            int2 m = make_int2(-1, 0);
#pragma unroll
            for (int d = 0; d < ND; d++) {
                const int ti = i - (base[d] >> 7);
                if (ti >= 0 && ti < ntc[d]) m = make_int2(d, base[d] + (ti << 7));
            }
            meta[i] = m;
        }
        return;
    }
    // ---- position assignment ----
    __shared__ int lcnt[ND];
    __shared__ int lbase[ND];
    if (tid < ND) lcnt[tid] = 0;
    __syncthreads();
    const int r = blockIdx.x * 256 + tid;
    const int d = dt[r];
    const int myrank = atomicAdd(&lcnt[d], 1);   // LDS atomic: cheap
    __syncthreads();
    if (tid < ND) {
        int base = 0;
        for (int dd = 0; dd < tid; dd++) base += ((counts[dd] + 127) >> 7) << 7;
        lbase[tid] = base + (lcnt[tid] > 0 ? atomicAdd(&cursors[tid], lcnt[tid]) : 0);
    }
    __syncthreads();
    perm[lbase[d] + myrank] = r;
}

// ---------------- 3. gather copy (perm-driven): one wave per dest row ---------
__global__ __launch_bounds__(256)
void copy_rows(const float* __restrict__ x, const int* __restrict__ perm,
               unsigned short* __restrict__ xs) {
    const int tid = threadIdx.x;
    const int lane = tid & 63;
    const int p = blockIdx.x * 4 + (tid >> 6);           // 4 dest rows per block
    const int r = perm[p];
    if (r < 0) return;                                   // padding row
    float4 v = ((const float4*)(x + (size_t)r * DIN))[lane];   // 16B/lane read
    ushort4 o;
    o.x = f2bf(v.x); o.y = f2bf(v.y); o.z = f2bf(v.z); o.w = f2bf(v.w);
    ((ushort4*)(xs + (size_t)p * DIN))[lane] = o;              // 8B/lane write
}

// ---------------- 4. GEMM-A: H = XS @ W1^T + b1, LN partials ------------------
// 128x128 tile, 4 waves 2x2, BK=32, dbuf single-barrier (round-13 exact).
__global__ __launch_bounds__(256, 2)
void gemm_a(const unsigned short* __restrict__ A,
            const unsigned short* __restrict__ Bt,
            const float* __restrict__ bias,
            const int2* __restrict__ meta,
            unsigned short* __restrict__ Cbf,
            float2* __restrict__ spart) {
    constexpr int K = DIN, Ntot = DHID, NB = 8, NWG = NTILES * NB, NS = K / 32;
    const int bid = (int)blockIdx.x;
    const int wid = (bid & 7) * (NWG >> 3) + (bid >> 3);
    const int tile = wid / NB;
    const int n0 = (wid % NB) * 128;
    const int2 md = meta[tile];
    const int dom = md.x;
    if (dom < 0) return;
    const int m0 = md.y;

    __shared__ unsigned short As[2][128 * 32];
    __shared__ unsigned short Bs[2][128 * 32];
    __shared__ float sred[2][128];

    const int tid = threadIdx.x;
    const int lane = tid & 63;
    const int w = tid >> 6;
    const int wr = w >> 1, wc = w & 1;
    const int l15 = lane & 15;

    const unsigned short* Abase = A + (size_t)m0 * K;
    const unsigned short* Bbase = Bt + (size_t)dom * Ntot * K + (size_t)n0 * K;

    if (tid < 128) { sred[0][tid] = 0.f; sred[1][tid] = 0.f; }

#define STAGE_AB(buf, t_) {                                                    \
        const int k0_ = (t_) * 32;                                             \
        _Pragma("unroll")                                                      \
        for (int it = 0; it < 2; ++it) {                                       \
            const int c = w * 128 + it * 64 + lane;                            \
            const int m_ = c >> 2, kcc = c & 3;                                \
            GLDS16(Bbase + (size_t)m_ * K + k0_ + kcc * 8,                     \
                   &Bs[buf][(w * 128 + it * 64) * 8]);                         \
            GLDS16(Abase + (size_t)m_ * K + k0_ + kcc * 8,                     \
                   &As[buf][(w * 128 + it * 64) * 8]);                         \
        }                                                                      \
    }

    floatx4 acc[4][4];
#pragma unroll
    for (int i = 0; i < 4; i++)
#pragma unroll
        for (int j = 0; j < 4; j++) acc[i][j] = 0.f;

    STAGE_AB(0, 0)
    __syncthreads();

    int cur = 0;
    const int kk = (lane >> 4) * 8;
    for (int t = 0; t < NS - 1; ++t) {
        const int nx = cur ^ 1;
        STAGE_AB(nx, t + 1)
        short8 a[4], b[4];
#pragma unroll
        for (int i = 0; i < 4; i++) {
            const int m = wr * 64 + i * 16 + l15;
            a[i] = *(const short8*)&As[cur][m * 32 + kk];
            const int n = wc * 64 + i * 16 + l15;
            b[i] = *(const short8*)&Bs[cur][n * 32 + kk];
        }
        __builtin_amdgcn_s_setprio(1);
#pragma unroll
        for (int i = 0; i < 4; i++)
#pragma unroll
            for (int j = 0; j < 4; j++)
                acc[i][j] = __builtin_amdgcn_mfma_f32_16x16x32_bf16(a[i], b[j], acc[i][j], 0, 0, 0);
        __builtin_amdgcn_s_setprio(0);
        __syncthreads();
        cur = nx;
    }
    {
        short8 a[4], b[4];
#pragma unroll
        for (int i = 0; i < 4; i++) {
            const int m = wr * 64 + i * 16 + l15;
            a[i] = *(const short8*)&As[cur][m * 32 + kk];
            const int n = wc * 64 + i * 16 + l15;
            b[i] = *(const short8*)&Bs[cur][n * 32 + kk];
        }
        __builtin_amdgcn_s_setprio(1);
#pragma unroll
        for (int i = 0; i < 4; i++)
#pragma unroll
            for (int j = 0; j < 4; j++)
                acc[i][j] = __builtin_amdgcn_mfma_f32_16x16x32_bf16(a[i], b[j], acc[i][j], 0, 0, 0);
        __builtin_amdgcn_s_setprio(0);
    }
#undef STAGE_AB

    // epilogue: write H = h+b1 (bf16) + per-row LN partials
    const int quad = lane >> 4;
    float bv[4];
#pragma unroll
    for (int j = 0; j < 4; j++)
        bv[j] = bias[dom * Ntot + n0 + wc * 64 + j * 16 + l15];
#pragma unroll
    for (int i = 0; i < 4; i++) {
#pragma unroll
        for (int r = 0; r < 4; r++) {
            const int rl = wr * 64 + i * 16 + quad * 4 + r;
            float s = 0.f, s2 = 0.f;
#pragma unroll
            for (int j = 0; j < 4; j++) {
                const float v = acc[i][j][r] + bv[j];
                Cbf[(size_t)(m0 + rl) * Ntot + n0 + wc * 64 + j * 16 + l15] = f2bf(v);
                s += v; s2 += v * v;
            }
#pragma unroll
            for (int o = 8; o; o >>= 1) {
                s  += __shfl_xor(s, o, 64);
                s2 += __shfl_xor(s2, o, 64);
            }
            if (l15 == 0) {
                atomicAdd(&sred[0][rl], s);
                atomicAdd(&sred[1][rl], s2);
            }
        }
    }
    __syncthreads();
    if (tid < 128)
        spart[(size_t)(n0 >> 7) * MPAD + m0 + tid] =
            make_float2(sred[0][tid], sred[1][tid]);
}

// ---------------- 5. GEMM-B: out = LN_ReLU(H) @ W2^T + b2 --------------------
// Round-13 exact: 128x128 tile, BK=32, dbuf single-barrier, A reg-staged with
// LN+ReLU transform (spart stats, gamma/beta from LDS), scatter via perm.
__global__ __launch_bounds__(256, 2)
void gemm_b(const unsigned short* __restrict__ H,
            const unsigned short* __restrict__ W2T,
            const float* __restrict__ b2,
            const int2* __restrict__ meta,
            const int* __restrict__ perm,
            float* __restrict__ out,
            const float2* __restrict__ spart,
            const float* __restrict__ gamma,
            const float* __restrict__ beta) {
    constexpr int K = DHID;
    constexpr int NWG = NTILES * 2;           // 528
    constexpr int NS = K / 32;                // 32 steps
    const int bid = (int)blockIdx.x;
    const int wid = (bid & 7) * (NWG >> 3) + (bid >> 3);
    const int tile = wid >> 1;
    const int n0 = (wid & 1) * 128;
    const int2 md = meta[tile];
    const int dom = md.x;
    if (dom < 0) return;
    const int m0 = md.y;

    __shared__ unsigned short As[2][128 * 32];   // 2 x 8 KB
    __shared__ unsigned short Bs[2][128 * 32];   // 2 x 8 KB
    __shared__ float gb[2048];                   // gamma[1024] beta[1024]

    const int tid = threadIdx.x;
    const int lane = tid & 63;
    const int w = tid >> 6;
    const int wr = w >> 1, wc = w & 1;
    const int l15 = lane & 15;

    const unsigned short* Hbase = H + (size_t)m0 * K;
    const unsigned short* Bbase = W2T + (size_t)dom * DOUT * K + (size_t)n0 * K;

    // gamma/beta -> LDS (read after the first barrier)
    ((float4*)gb)[tid] = ((const float4*)(gamma + dom * DHID))[tid];
    ((float4*)(gb + 1024))[tid] = ((const float4*)(beta + dom * DHID))[tid];

    const int ma = (w * 128 + lane) >> 2;    // staged rows ma, ma+16
    const int kc = lane & 3;                 // fixed 16B k-chunk within 32
    float muv[2], rsv[2];
#pragma unroll
    for (int h2 = 0; h2 < 2; ++h2) {
        const int rm = m0 + ma + h2 * 16;
        float s = 0.f, s2 = 0.f;
#pragma unroll
        for (int nb = 0; nb < 8; ++nb) {
            const float2 p = spart[(size_t)nb * MPAD + rm];
            s += p.x; s2 += p.y;
        }
        const float mu = s * (1.f / 1024.f);
        const float var = fmaxf(s2 * (1.f / 1024.f) - mu * mu, 0.f);
        muv[h2] = mu;
        rsv[h2] = rsqrtf(var + 1e-5f);
    }
    short8 hv0{}, hv1{};

#define LOAD_H(t_) {                                                           \
        const int k0_ = (t_) * 32 + kc * 8;                                    \
        hv0 = *(const short8*)(Hbase + (size_t)ma * K + k0_);                  \
        hv1 = *(const short8*)(Hbase + (size_t)(ma + 16) * K + k0_);           \
    }
#define XFRM(buf, t_) {                                                        \
        const int k1 = (t_) * 32 + kc * 8;                                     \
        const float4 g0 = *(const float4*)&gb[k1];                             \
        const float4 g1 = *(const float4*)&gb[k1 + 4];                         \
        const float4 e0 = *(const float4*)&gb[1024 + k1];                      \
        const float4 e1 = *(const float4*)&gb[1024 + k1 + 4];                  \
        const float gA[8] = {g0.x, g0.y, g0.z, g0.w, g1.x, g1.y, g1.z, g1.w};  \
        const float eA[8] = {e0.x, e0.y, e0.z, e0.w, e1.x, e1.y, e1.z, e1.w};  \
        _Pragma("unroll")                                                      \
        for (int h2 = 0; h2 < 2; ++h2) {                                       \
            const float mu = muv[h2], rs = rsv[h2];                            \
            const short8 hvv = h2 ? hv1 : hv0;                                 \
            short8 o;                                                          \
            _Pragma("unroll")                                                  \
            for (int e = 0; e < 8; ++e) {                                      \
                const float rg = gA[e] * rs;                                   \
                const float v = fmaxf(fmaf(bf2f((unsigned short)hvv[e]), rg,   \
                                           fmaf(-mu, rg, eA[e])), 0.f);        \
                o[e] = (short)f2bf(v);                                         \
            }                                                                  \
            *(short8*)&As[buf][(w * 128 + h2 * 64 + lane) * 8] = o;            \
        }                                                                      \
    }
#define STAGE_B(buf, t_) {                                                     \
        const int k0_ = (t_) * 32;                                             \
        _Pragma("unroll")                                                      \
        for (int it = 0; it < 2; ++it) {                                       \
            const int c = w * 128 + it * 64 + lane;                            \
            const int m_ = c >> 2, kcc = c & 3;                                \
            GLDS16(Bbase + (size_t)m_ * K + k0_ + kcc * 8,                     \
                   &Bs[buf][(w * 128 + it * 64) * 8]);                         \
        }                                                                      \
    }

    floatx4 acc[4][4];
#pragma unroll
    for (int i = 0; i < 4; i++)
#pragma unroll
        for (int j = 0; j < 4; j++) acc[i][j] = 0.f;

    // prologue
    STAGE_B(0, 0)
    LOAD_H(0)
    __syncthreads();       // gb LDS writes visible to all waves
    XFRM(0, 0)             // uses H(0) regs (auto-waited)
    LOAD_H(1)
    __syncthreads();       // As[0] ds_writes + Bs[0] GLDS drained

    int cur = 0;
    const int kk = (lane >> 4) * 8;
    for (int t = 0; t < NS - 1; ++t) {
        const int nx = cur ^ 1;
        STAGE_B(nx, t + 1)
        XFRM(nx, t + 1)                 // uses H(t+1)
        if (t + 2 < NS) LOAD_H(t + 2)
        short8 a[4], b[4];
#pragma unroll
        for (int i = 0; i < 4; i++) {
            const int m = wr * 64 + i * 16 + l15;
            a[i] = *(const short8*)&As[cur][m * 32 + kk];
            const int n = wc * 64 + i * 16 + l15;
            b[i] = *(const short8*)&Bs[cur][n * 32 + kk];
        }
        __builtin_amdgcn_s_setprio(1);
#pragma unroll
        for (int i = 0; i < 4; i++)
#pragma unroll
            for (int j = 0; j < 4; j++)
                acc[i][j] = __builtin_amdgcn_mfma_f32_16x16x32_bf16(a[i], b[j], acc[i][j], 0, 0, 0);
        __builtin_amdgcn_s_setprio(0);
        __syncthreads();
        cur = nx;
    }
    {
        short8 a[4], b[4];
#pragma unroll
        for (int i = 0; i < 4; i++) {
            const int m = wr * 64 + i * 16 + l15;
            a[i] = *(const short8*)&As[cur][m * 32 + kk];
            const int n = wc * 64 + i * 16 + l15;
            b[i] = *(const short8*)&Bs[cur][n * 32 + kk];
        }
        __builtin_amdgcn_s_setprio(1);
#pragma unroll
        for (int i = 0; i < 4; i++)
#pragma unroll
            for (int j = 0; j < 4; j++)
                acc[i][j] = __builtin_amdgcn_mfma_f32_16x16x32_bf16(a[i], b[j], acc[i][j], 0, 0, 0);
        __builtin_amdgcn_s_setprio(0);
    }
#undef LOAD_H
#undef XFRM
#undef STAGE_B

    // epilogue: scatter out = acc + b2 via perm (padding rows skipped)
    const int quad = lane >> 4;
    float bv[4];
#pragma unroll
    for (int j = 0; j < 4; j++)
        bv[j] = b2[dom * DOUT + n0 + wc * 64 + j * 16 + l15];
#pragma unroll
    for (int i = 0; i < 4; i++) {
        const int rowbase = m0 + wr * 64 + i * 16 + quad * 4;
#pragma unroll
        for (int r = 0; r < 4; r++) {
            const int orig = perm[rowbase + r];
            if (orig < 0) continue;     // padding row
#pragma unroll
            for (int j = 0; j < 4; j++) {
                const int col = n0 + wc * 64 + j * 16 + l15;
                out[(size_t)orig * DOUT + col] = acc[i][j][r] + bv[j];
            }
        }
    }
}

// ---------------- launch ------------------------------------------------------
extern "C" void kernel_launch(void* const* d_in, const int* in_sizes, int n_in,
                              void* d_out, int out_size, void* d_ws, size_t ws_size,
                              hipStream_t stream) {
    const float* x = (const float*)d_in[0];
    const int* dt = (const int*)d_in[1];
    const float* W1 = (const float*)d_in[2];
    const float* b1 = (const float*)d_in[3];
    const float* gamma = (const float*)d_in[4];
    const float* beta = (const float*)d_in[5];
    const float* W2 = (const float*)d_in[6];
    const float* b2 = (const float*)d_in[7];
    float* out = (float*)d_out;

    char* ws = (char*)d_ws;
    size_t off = 0;
    auto take = [&](size_t nbytes) -> char* {
        char* p = ws + off;
        off = (off + nbytes + 255) & ~(size_t)255;
        return p;
    };
    unsigned short* W1T = (unsigned short*)take((size_t)ND * DHID * DIN * 2);
    unsigned short* W2T = (unsigned short*)take((size_t)ND * DOUT * DHID * 2);
    unsigned short* XS  = (unsigned short*)take((size_t)MPAD * DIN * 2);
    unsigned short* H   = (unsigned short*)take((size_t)MPAD * DHID * 2);
    float2* SPART = (float2*)take((size_t)8 * MPAD * 8);
    int* PERM   = (int*)take(MPAD * 4);
    int* CNT    = (int*)take(64);            // counts[8] then cursors[8]
    int2* META  = (int2*)take(NTILES * 8);
    (void)ws_size; (void)n_in; (void)in_sizes; (void)out_size;

    int* COUNTS = CNT;
    int* CURSORS = CNT + 8;

    hipMemsetAsync(CNT, 0, 64, stream);      // counts + cursors
    prep1<<<4356, 256, 0, stream>>>(W1, W1T, W2, W2T, dt, PERM, COUNTS);
    assign_meta<<<129, 256, 0, stream>>>(dt, COUNTS, CURSORS, PERM, META);
    copy_rows<<<MPAD / 4, 256, 0, stream>>>(x, PERM, XS);
    gemm_a<<<NTILES * 8, 256, 0, stream>>>(XS, W1T, b1, META, H, SPART);
    gemm_b<<<NTILES * 2, 256, 0, stream>>>(H, W2T, b2, META, PERM, out,
                                           SPART, gamma, beta);
}